// Round 1
// baseline (2881.729 us; speedup 1.0000x reference)
//
#include <hip/hip_runtime.h>

#define NN 50000
#define NE 800000
#define D 128

// ---------------- degree / norm ----------------
__global__ __launch_bounds__(256) void k_deg_init(float* __restrict__ deg) {
    int i = blockIdx.x * 256 + threadIdx.x;
    if (i < NN) deg[i] = 1.0f;   // self-loop
}

__global__ __launch_bounds__(256) void k_deg_count(const int* __restrict__ dst, float* __restrict__ deg) {
    int e = blockIdx.x * 256 + threadIdx.x;
    if (e < NE) atomicAdd(&deg[dst[e]], 1.0f);
}

__global__ __launch_bounds__(256) void k_dinv(float* __restrict__ deg) {
    int i = blockIdx.x * 256 + threadIdx.x;
    if (i < NN) deg[i] = rsqrtf(deg[i]);
}

// ---------------- GEMM: H[M,128] = act(A[M,128]) @ W[128,128] ----------------
// block = 256 threads, tile = 32 rows x 128 cols, 4x4 register blocking.
template <bool RELU_IN>
__global__ __launch_bounds__(256) void k_gemm(const float* __restrict__ A, const float* __restrict__ W,
                                              float* __restrict__ H) {
    __shared__ float Wl[D][D];   // 64 KB
    __shared__ float Xl[32][D];  // 16 KB
    const int t = threadIdx.x;

    // stage W (row-major [k][c]) — 16 float4 per thread, coalesced
    const float4* W4 = (const float4*)W;
    float4* Wl4 = (float4*)&Wl[0][0];
#pragma unroll
    for (int i = 0; i < 16; ++i) {
        int lin = i * 256 + t;
        Wl4[lin] = W4[lin];
    }

    // stage 32-row x tile
    const int r0 = blockIdx.x * 32;
    {
        int row = t >> 3;        // 0..31
        int lane8 = t & 7;       // 8 threads per row
        int gr = r0 + row;
#pragma unroll
        for (int i = 0; i < 4; ++i) {
            int k4 = lane8 + i * 8;  // float4 idx in row
            float4 v;
            if (gr < NN) {
                v = ((const float4*)(A + (size_t)gr * D))[k4];
                if (RELU_IN) {
                    v.x = fmaxf(v.x, 0.f); v.y = fmaxf(v.y, 0.f);
                    v.z = fmaxf(v.z, 0.f); v.w = fmaxf(v.w, 0.f);
                }
            } else {
                v = make_float4(0.f, 0.f, 0.f, 0.f);
            }
            ((float4*)&Xl[row][0])[k4] = v;
        }
    }
    __syncthreads();

    const int ct = t & 31;   // col group: cols 4*ct..4*ct+3
    const int rt = t >> 5;   // row group: rows 4*rt..4*rt+3
    float acc[4][4];
#pragma unroll
    for (int j = 0; j < 4; ++j)
#pragma unroll
        for (int i = 0; i < 4; ++i) acc[j][i] = 0.f;

#pragma unroll 8
    for (int k = 0; k < D; ++k) {
        float4 wb = ((const float4*)&Wl[k][0])[ct];
        float x0 = Xl[4 * rt + 0][k];
        float x1 = Xl[4 * rt + 1][k];
        float x2 = Xl[4 * rt + 2][k];
        float x3 = Xl[4 * rt + 3][k];
        acc[0][0] += x0 * wb.x; acc[0][1] += x0 * wb.y; acc[0][2] += x0 * wb.z; acc[0][3] += x0 * wb.w;
        acc[1][0] += x1 * wb.x; acc[1][1] += x1 * wb.y; acc[1][2] += x1 * wb.z; acc[1][3] += x1 * wb.w;
        acc[2][0] += x2 * wb.x; acc[2][1] += x2 * wb.y; acc[2][2] += x2 * wb.z; acc[2][3] += x2 * wb.w;
        acc[3][0] += x3 * wb.x; acc[3][1] += x3 * wb.y; acc[3][2] += x3 * wb.z; acc[3][3] += x3 * wb.w;
    }

#pragma unroll
    for (int j = 0; j < 4; ++j) {
        int gr = r0 + 4 * rt + j;
        if (gr < NN) {
            float4 v = make_float4(acc[j][0], acc[j][1], acc[j][2], acc[j][3]);
            ((float4*)(H + (size_t)gr * D))[ct] = v;
        }
    }
}

// ---------------- out[j] = h[j]*dinv[j]^2 + b  (scatter destination init) ----------------
__global__ __launch_bounds__(256) void k_agg_init(const float* __restrict__ H, const float* __restrict__ dinv,
                                                  const float* __restrict__ b, float* __restrict__ agg) {
    int tid = blockIdx.x * 256 + threadIdx.x;  // over NN*32
    int node = tid >> 5, q = tid & 31;
    if (node >= NN) return;
    float di = dinv[node];
    float s = di * di;
    float4 h = ((const float4*)(H + (size_t)node * D))[q];
    float4 bb = ((const float4*)b)[q];
    float4 o = make_float4(fmaf(h.x, s, bb.x), fmaf(h.y, s, bb.y),
                           fmaf(h.z, s, bb.z), fmaf(h.w, s, bb.w));
    ((float4*)(agg + (size_t)node * D))[q] = o;
}

// ---------------- edge scatter: agg[dst] += dinv[src]*dinv[dst]*h[src] ----------------
__global__ __launch_bounds__(256) void k_scatter(const int* __restrict__ src, const int* __restrict__ dst,
                                                 const float* __restrict__ dinv, const float* __restrict__ H,
                                                 float* __restrict__ agg) {
    int tid = blockIdx.x * 256 + threadIdx.x;  // over NE*32 = 25.6M
    int e = tid >> 5, q = tid & 31;
    if (e >= NE) return;
    int s = src[e], d = dst[e];
    float c = dinv[s] * dinv[d];
    float4 h = ((const float4*)(H + (size_t)s * D))[q];
    float* base = agg + (size_t)d * D + 4 * q;
    atomicAdd(base + 0, h.x * c);
    atomicAdd(base + 1, h.y * c);
    atomicAdd(base + 2, h.z * c);
    atomicAdd(base + 3, h.w * c);
}

extern "C" void kernel_launch(void* const* d_in, const int* in_sizes, int n_in,
                              void* d_out, int out_size, void* d_ws, size_t ws_size,
                              hipStream_t stream) {
    const float* x  = (const float*)d_in[0];
    const int*   ei = (const int*)d_in[1];     // [2][NE]: src then dst
    const float* W1 = (const float*)d_in[2];
    const float* b1 = (const float*)d_in[3];
    const float* W2 = (const float*)d_in[4];
    const float* b2 = (const float*)d_in[5];
    float* out = (float*)d_out;

    const int* src = ei;
    const int* dst = ei + NE;

    char* ws = (char*)d_ws;
    float* dinv = (float*)ws;                          // NN floats (200 KB, padded to 256 KB)
    float* h    = (float*)(ws + 262144);               // NN*D floats (25.6 MB)
    float* agg  = (float*)(ws + 262144 + (size_t)NN * D * 4);  // NN*D floats

    const int nBlkNode   = (NN + 255) / 256;           // 196
    const int nBlkEdge   = (NE + 255) / 256;           // 3125
    const int nBlkGemm   = (NN + 31) / 32;             // 1563
    const int nBlkNode32 = (NN * 32) / 256;            // 6250
    const int nBlkEdge32 = (NE * 32) / 256;            // 100000

    // degree + rsqrt norm
    k_deg_init<<<nBlkNode, 256, 0, stream>>>(dinv);
    k_deg_count<<<nBlkEdge, 256, 0, stream>>>(dst, dinv);
    k_dinv<<<nBlkNode, 256, 0, stream>>>(dinv);

    // layer 1
    k_gemm<false><<<nBlkGemm, 256, 0, stream>>>(x, W1, h);
    k_agg_init<<<nBlkNode32, 256, 0, stream>>>(h, dinv, b1, agg);
    k_scatter<<<nBlkEdge32, 256, 0, stream>>>(src, dst, dinv, h, agg);

    // layer 2 (ReLU folded into GEMM input load)
    k_gemm<true><<<nBlkGemm, 256, 0, stream>>>(agg, W2, h);
    k_agg_init<<<nBlkNode32, 256, 0, stream>>>(h, dinv, b2, out);
    k_scatter<<<nBlkEdge32, 256, 0, stream>>>(src, dst, dinv, h, out);
}

// Round 2
// 358.980 us; speedup vs baseline: 8.0276x; 8.0276x over previous
//
#include <hip/hip_runtime.h>

#define NN 50000
#define NE 800000
#define D 128
#define NBLK ((NN + 255) / 256)   // 196 blocks over nodes

// ---------------- CSR build ----------------
__global__ __launch_bounds__(256) void k_zero_cnt(int* __restrict__ cnt) {
    int i = blockIdx.x * 256 + threadIdx.x;
    if (i < NN) cnt[i] = 0;
}

__global__ __launch_bounds__(256) void k_count(const int* __restrict__ dst, int* __restrict__ cnt) {
    int e = blockIdx.x * 256 + threadIdx.x;
    if (e < NE) atomicAdd(&cnt[dst[e]], 1);
}

__global__ __launch_bounds__(256) void k_dinv(const int* __restrict__ cnt, float* __restrict__ dinv) {
    int i = blockIdx.x * 256 + threadIdx.x;
    if (i < NN) dinv[i] = rsqrtf((float)cnt[i] + 1.0f);  // +1 self-loop
}

__global__ __launch_bounds__(256) void k_scan_partial(const int* __restrict__ cnt, int* __restrict__ blockSums) {
    __shared__ int s[256];
    int t = threadIdx.x;
    int i = blockIdx.x * 256 + t;
    s[t] = (i < NN) ? cnt[i] : 0;
    __syncthreads();
    for (int off = 128; off > 0; off >>= 1) {
        if (t < off) s[t] += s[t + off];
        __syncthreads();
    }
    if (t == 0) blockSums[blockIdx.x] = s[0];
}

__global__ __launch_bounds__(256) void k_scan_blocks(int* __restrict__ blockSums, int* __restrict__ row_ptr) {
    __shared__ int s[256];
    int t = threadIdx.x;
    int v = (t < NBLK) ? blockSums[t] : 0;
    s[t] = v;
    __syncthreads();
    for (int off = 1; off < 256; off <<= 1) {
        int y = (t >= off) ? s[t - off] : 0;
        __syncthreads();
        s[t] += y;
        __syncthreads();
    }
    if (t < NBLK) blockSums[t] = s[t] - v;  // exclusive block offsets
    if (t == 0) row_ptr[NN] = NE;
}

__global__ __launch_bounds__(256) void k_scan_final(const int* __restrict__ cnt, const int* __restrict__ blockOffs,
                                                    int* __restrict__ row_ptr, int* __restrict__ cursor) {
    __shared__ int s[256];
    int t = threadIdx.x;
    int i = blockIdx.x * 256 + t;
    int v = (i < NN) ? cnt[i] : 0;
    s[t] = v;
    __syncthreads();
    for (int off = 1; off < 256; off <<= 1) {
        int y = (t >= off) ? s[t - off] : 0;
        __syncthreads();
        s[t] += y;
        __syncthreads();
    }
    if (i < NN) {
        int excl = s[t] - v + blockOffs[blockIdx.x];
        row_ptr[i] = excl;
        cursor[i] = excl;
    }
}

__global__ __launch_bounds__(256) void k_fill(const int* __restrict__ src, const int* __restrict__ dst,
                                              const float* __restrict__ dinv, int* __restrict__ cursor,
                                              int* __restrict__ csr_src, float* __restrict__ csr_coef) {
    int e = blockIdx.x * 256 + threadIdx.x;
    if (e < NE) {
        int sN = src[e], dN = dst[e];
        int pos = atomicAdd(&cursor[dN], 1);
        csr_src[pos] = sN;
        csr_coef[pos] = dinv[sN] * dinv[dN];
    }
}

// ---------------- GEMM: H[M,128] = act(A[M,128]) @ W[128,128] ----------------
template <bool RELU_IN>
__global__ __launch_bounds__(256) void k_gemm(const float* __restrict__ A, const float* __restrict__ W,
                                              float* __restrict__ H) {
    __shared__ float Wl[D][D];   // 64 KB
    __shared__ float Xl[32][D];  // 16 KB
    const int t = threadIdx.x;

    const float4* W4 = (const float4*)W;
    float4* Wl4 = (float4*)&Wl[0][0];
#pragma unroll
    for (int i = 0; i < 16; ++i) {
        int lin = i * 256 + t;
        Wl4[lin] = W4[lin];
    }

    const int r0 = blockIdx.x * 32;
    {
        int row = t >> 3;
        int lane8 = t & 7;
        int gr = r0 + row;
#pragma unroll
        for (int i = 0; i < 4; ++i) {
            int k4 = lane8 + i * 8;
            float4 v;
            if (gr < NN) {
                v = ((const float4*)(A + (size_t)gr * D))[k4];
                if (RELU_IN) {
                    v.x = fmaxf(v.x, 0.f); v.y = fmaxf(v.y, 0.f);
                    v.z = fmaxf(v.z, 0.f); v.w = fmaxf(v.w, 0.f);
                }
            } else {
                v = make_float4(0.f, 0.f, 0.f, 0.f);
            }
            ((float4*)&Xl[row][0])[k4] = v;
        }
    }
    __syncthreads();

    const int ct = t & 31;
    const int rt = t >> 5;
    float acc[4][4];
#pragma unroll
    for (int j = 0; j < 4; ++j)
#pragma unroll
        for (int i = 0; i < 4; ++i) acc[j][i] = 0.f;

#pragma unroll 8
    for (int k = 0; k < D; ++k) {
        float4 wb = ((const float4*)&Wl[k][0])[ct];
        float x0 = Xl[4 * rt + 0][k];
        float x1 = Xl[4 * rt + 1][k];
        float x2 = Xl[4 * rt + 2][k];
        float x3 = Xl[4 * rt + 3][k];
        acc[0][0] += x0 * wb.x; acc[0][1] += x0 * wb.y; acc[0][2] += x0 * wb.z; acc[0][3] += x0 * wb.w;
        acc[1][0] += x1 * wb.x; acc[1][1] += x1 * wb.y; acc[1][2] += x1 * wb.z; acc[1][3] += x1 * wb.w;
        acc[2][0] += x2 * wb.x; acc[2][1] += x2 * wb.y; acc[2][2] += x2 * wb.z; acc[2][3] += x2 * wb.w;
        acc[3][0] += x3 * wb.x; acc[3][1] += x3 * wb.y; acc[3][2] += x3 * wb.z; acc[3][3] += x3 * wb.w;
    }

#pragma unroll
    for (int j = 0; j < 4; ++j) {
        int gr = r0 + 4 * rt + j;
        if (gr < NN) {
            float4 v = make_float4(acc[j][0], acc[j][1], acc[j][2], acc[j][3]);
            ((float4*)(H + (size_t)gr * D))[ct] = v;
        }
    }
}

// ---------------- pull aggregation: one wave per node ----------------
// out[node] = h[node]*dinv^2 + b + sum_in coef*h[src]
__global__ __launch_bounds__(256) void k_pull(const float* __restrict__ H, const float* __restrict__ dinv,
                                              const float* __restrict__ b, const int* __restrict__ row_ptr,
                                              const int* __restrict__ csr_src, const float* __restrict__ csr_coef,
                                              float* __restrict__ out) {
    int wid = (blockIdx.x * 256 + threadIdx.x) >> 6;
    int lane = threadIdx.x & 63;
    int node = __builtin_amdgcn_readfirstlane(wid);  // wave-uniform -> scalar loads below

    const float2* H2 = (const float2*)H;
    float di = dinv[node];
    float s2 = di * di;
    float2 acc = H2[(size_t)node * 64 + lane];
    float2 bb = ((const float2*)b)[lane];
    acc.x = fmaf(acc.x, s2, bb.x);
    acc.y = fmaf(acc.y, s2, bb.y);

    int beg = row_ptr[node];
    int end = row_ptr[node + 1];
    for (int i = beg; i < end; ++i) {
        int s = csr_src[i];        // wave-uniform scalar load
        float c = csr_coef[i];     // wave-uniform scalar load
        float2 v = H2[(size_t)s * 64 + lane];  // coalesced 512B row gather
        acc.x = fmaf(v.x, c, acc.x);
        acc.y = fmaf(v.y, c, acc.y);
    }
    ((float2*)out)[(size_t)node * 64 + lane] = acc;
}

extern "C" void kernel_launch(void* const* d_in, const int* in_sizes, int n_in,
                              void* d_out, int out_size, void* d_ws, size_t ws_size,
                              hipStream_t stream) {
    const float* x  = (const float*)d_in[0];
    const int*   ei = (const int*)d_in[1];
    const float* W1 = (const float*)d_in[2];
    const float* b1 = (const float*)d_in[3];
    const float* W2 = (const float*)d_in[4];
    const float* b2 = (const float*)d_in[5];
    float* out = (float*)d_out;

    const int* src = ei;
    const int* dst = ei + NE;

    char* ws = (char*)d_ws;
    float* dinv      = (float*)(ws + 0);          // 200000 B
    int*   cnt       = (int*)  (ws + 204800);     // 200000 B
    int*   row_ptr   = (int*)  (ws + 409600);     // 200004 B
    int*   cursor    = (int*)  (ws + 614400);     // 200000 B
    int*   blockSums = (int*)  (ws + 819200);     // 784 B
    int*   csr_src   = (int*)  (ws + 820224);     // 3.2 MB
    float* csr_coef  = (float*)(ws + 4020224);    // 3.2 MB
    float* h         = (float*)(ws + 7220224);    // 25.6 MB

    const int nBlkEdge = (NE + 255) / 256;   // 3125
    const int nBlkGemm = (NN + 31) / 32;     // 1563
    const int nBlkPull = NN / 4;             // 12500 (4 waves/block, 1 wave/node)

    // CSR build + norm
    k_zero_cnt<<<NBLK, 256, 0, stream>>>(cnt);
    k_count<<<nBlkEdge, 256, 0, stream>>>(dst, cnt);
    k_dinv<<<NBLK, 256, 0, stream>>>(cnt, dinv);
    k_scan_partial<<<NBLK, 256, 0, stream>>>(cnt, blockSums);
    k_scan_blocks<<<1, 256, 0, stream>>>(blockSums, row_ptr);
    k_scan_final<<<NBLK, 256, 0, stream>>>(cnt, blockSums, row_ptr, cursor);
    k_fill<<<nBlkEdge, 256, 0, stream>>>(src, dst, dinv, cursor, csr_src, csr_coef);

    // layer 1  (d_out doubles as the layer-1 aggregation buffer)
    k_gemm<false><<<nBlkGemm, 256, 0, stream>>>(x, W1, h);
    k_pull<<<nBlkPull, 256, 0, stream>>>(h, dinv, b1, row_ptr, csr_src, csr_coef, out);

    // layer 2 (ReLU folded into GEMM input load)
    k_gemm<true><<<nBlkGemm, 256, 0, stream>>>(out, W2, h);
    k_pull<<<nBlkPull, 256, 0, stream>>>(h, dinv, b2, row_ptr, csr_src, csr_coef, out);
}

// Round 3
// 356.887 us; speedup vs baseline: 8.0746x; 1.0059x over previous
//
#include <hip/hip_runtime.h>

#define NN 50000
#define NE 800000
#define D 128
#define NBLK ((NN + 255) / 256)   // 196 blocks over nodes

typedef __attribute__((ext_vector_type(8))) short bf16x8;
typedef __attribute__((ext_vector_type(4))) float f32x4;

static __device__ __forceinline__ unsigned short f2bf(float f) {
    unsigned u = __builtin_bit_cast(unsigned, f);
    unsigned r = (u + 0x7fffu + ((u >> 16) & 1u)) >> 16;   // RN-even
    return (unsigned short)r;
}
static __device__ __forceinline__ float bf2f(unsigned short h) {
    unsigned u = ((unsigned)h) << 16;
    return __builtin_bit_cast(float, u);
}

// ---------------- CSR build ----------------
__global__ __launch_bounds__(256) void k_zero_cnt(int* __restrict__ cnt) {
    int i = blockIdx.x * 256 + threadIdx.x;
    if (i < NN) cnt[i] = 0;
}

__global__ __launch_bounds__(256) void k_count(const int* __restrict__ dst, int* __restrict__ cnt) {
    int e = blockIdx.x * 256 + threadIdx.x;
    if (e < NE) atomicAdd(&cnt[dst[e]], 1);
}

__global__ __launch_bounds__(256) void k_dinv(const int* __restrict__ cnt, float* __restrict__ dinv) {
    int i = blockIdx.x * 256 + threadIdx.x;
    if (i < NN) dinv[i] = rsqrtf((float)cnt[i] + 1.0f);  // +1 self-loop
}

__global__ __launch_bounds__(256) void k_scan_partial(const int* __restrict__ cnt, int* __restrict__ blockSums) {
    __shared__ int s[256];
    int t = threadIdx.x;
    int i = blockIdx.x * 256 + t;
    s[t] = (i < NN) ? cnt[i] : 0;
    __syncthreads();
    for (int off = 128; off > 0; off >>= 1) {
        if (t < off) s[t] += s[t + off];
        __syncthreads();
    }
    if (t == 0) blockSums[blockIdx.x] = s[0];
}

__global__ __launch_bounds__(256) void k_scan_blocks(int* __restrict__ blockSums, int* __restrict__ row_ptr,
                                                     int* __restrict__ csr_src, float* __restrict__ csr_coef) {
    __shared__ int s[256];
    int t = threadIdx.x;
    int v = (t < NBLK) ? blockSums[t] : 0;
    s[t] = v;
    __syncthreads();
    for (int off = 1; off < 256; off <<= 1) {
        int y = (t >= off) ? s[t - off] : 0;
        __syncthreads();
        s[t] += y;
        __syncthreads();
    }
    if (t < NBLK) blockSums[t] = s[t] - v;  // exclusive block offsets
    if (t == 0) row_ptr[NN] = NE;
    if (t < 8) {               // zero the unroll padding past NE
        csr_src[NE + t] = 0;
        csr_coef[NE + t] = 0.0f;
    }
}

__global__ __launch_bounds__(256) void k_scan_final(const int* __restrict__ cnt, const int* __restrict__ blockOffs,
                                                    int* __restrict__ row_ptr, int* __restrict__ cursor) {
    __shared__ int s[256];
    int t = threadIdx.x;
    int i = blockIdx.x * 256 + t;
    int v = (i < NN) ? cnt[i] : 0;
    s[t] = v;
    __syncthreads();
    for (int off = 1; off < 256; off <<= 1) {
        int y = (t >= off) ? s[t - off] : 0;
        __syncthreads();
        s[t] += y;
        __syncthreads();
    }
    if (i < NN) {
        int excl = s[t] - v + blockOffs[blockIdx.x];
        row_ptr[i] = excl;
        cursor[i] = excl;
    }
}

__global__ __launch_bounds__(256) void k_fill(const int* __restrict__ src, const int* __restrict__ dst,
                                              const float* __restrict__ dinv, int* __restrict__ cursor,
                                              int* __restrict__ csr_src, float* __restrict__ csr_coef) {
    int e = blockIdx.x * 256 + threadIdx.x;
    if (e < NE) {
        int sN = src[e], dN = dst[e];
        int pos = atomicAdd(&cursor[dN], 1);
        csr_src[pos] = sN;
        csr_coef[pos] = dinv[sN] * dinv[dN];
    }
}

// ---------------- W prep: fp32 [k][n] -> swizzled bf16 hi/lo images of W^T [n][k] ----------------
// image: 32768 B hi, then 32768 B lo. byte offset of (n,k): (n*256 + k*2) ^ ((n&7)<<4)
__global__ __launch_bounds__(256) void k_prepw(const float* __restrict__ W1, const float* __restrict__ W2,
                                               char* __restrict__ img1, char* __restrict__ img2) {
    int b = blockIdx.x;
    const float* W = (b < 64) ? W1 : W2;
    char* img = (b < 64) ? img1 : img2;
    int e = (b & 63) * 256 + threadIdx.x;  // 0..16383
    int k = e >> 7, n = e & 127;
    float f = W[e];
    unsigned short hi = f2bf(f);
    float rem = f - bf2f(hi);
    unsigned short lo = f2bf(rem);
    unsigned off = (unsigned)((n << 8) + (k << 1)) ^ (unsigned)((n & 7) << 4);
    *(unsigned short*)(img + off) = hi;
    *(unsigned short*)(img + 32768 + off) = lo;
}

// ---------------- MFMA GEMM: H[M,128] = act(A[M,128]) @ W[128,128], bf16x3 split ----------------
// block = 256 threads (4 waves), 64 rows/block (16 rows/wave), full 128 cols.
template <bool RELU_IN>
__global__ __launch_bounds__(256) void k_mgemm(const float* __restrict__ A, const char* __restrict__ wimg,
                                               float* __restrict__ H) {
    __shared__ char lds[65536];
    const int t = threadIdx.x;

    {   // stage both swizzled bf16 images (byte-identical copy)
        const float4* gv = (const float4*)wimg;
        float4* lv = (float4*)lds;
#pragma unroll
        for (int i = 0; i < 16; ++i) lv[i * 256 + t] = gv[i * 256 + t];
    }
    __syncthreads();

    const int lane = t & 63;
    const int wv = t >> 6;                 // wave 0..3
    const int r0 = blockIdx.x * 64 + wv * 16;
    const int rl = lane & 15;              // A row in strip / C col
    const int g = lane >> 4;               // k-group 0..3
    int arow = r0 + rl;
    if (arow >= NN) arow = NN - 1;
    const float* ar = A + (size_t)arow * D + g * 8;

    f32x4 acc[8];
#pragma unroll
    for (int j = 0; j < 8; ++j) acc[j] = (f32x4){0.f, 0.f, 0.f, 0.f};

#pragma unroll
    for (int ks = 0; ks < 4; ++ks) {
        float av[8];
        float4 p0 = *(const float4*)(ar + ks * 32);
        float4 p1 = *(const float4*)(ar + ks * 32 + 4);
        av[0] = p0.x; av[1] = p0.y; av[2] = p0.z; av[3] = p0.w;
        av[4] = p1.x; av[5] = p1.y; av[6] = p1.z; av[7] = p1.w;
        bf16x8 ah, al;
#pragma unroll
        for (int i = 0; i < 8; ++i) {
            float a = RELU_IN ? fmaxf(av[i], 0.f) : av[i];
            unsigned short h = f2bf(a);
            ah[i] = (short)h;
            al[i] = (short)f2bf(a - bf2f(h));
        }
        const int kofs = (ks * 32 + g * 8) << 1;   // byte offset of k within row
#pragma unroll
        for (int j = 0; j < 8; ++j) {
            int n = j * 16 + rl;
            unsigned off = (unsigned)((n << 8) + kofs) ^ (unsigned)((n & 7) << 4);
            bf16x8 bh = *(const bf16x8*)(lds + off);
            bf16x8 bl = *(const bf16x8*)(lds + 32768 + off);
            acc[j] = __builtin_amdgcn_mfma_f32_16x16x32_bf16(ah, bh, acc[j], 0, 0, 0);
            acc[j] = __builtin_amdgcn_mfma_f32_16x16x32_bf16(ah, bl, acc[j], 0, 0, 0);
            acc[j] = __builtin_amdgcn_mfma_f32_16x16x32_bf16(al, bh, acc[j], 0, 0, 0);
        }
    }

    // C/D: col = lane&15, row = (lane>>4)*4 + reg  (m89-verified)
#pragma unroll
    for (int j = 0; j < 8; ++j) {
#pragma unroll
        for (int i = 0; i < 4; ++i) {
            int row = r0 + g * 4 + i;
            if (row < NN) H[(size_t)row * D + j * 16 + rl] = acc[j][i];
        }
    }
}

// ---------------- pull aggregation: one wave per node, 8-way edge unroll ----------------
__global__ __launch_bounds__(256) void k_pull(const float* __restrict__ H, const float* __restrict__ dinv,
                                              const float* __restrict__ b, const int* __restrict__ row_ptr,
                                              const int* __restrict__ csr_src, const float* __restrict__ csr_coef,
                                              float* __restrict__ out) {
    int wid = (blockIdx.x * 256 + threadIdx.x) >> 6;
    int lane = threadIdx.x & 63;
    int node = __builtin_amdgcn_readfirstlane(wid);

    const float2* H2 = (const float2*)H;
    float di = dinv[node];
    float s2 = di * di;
    float2 self = H2[(size_t)node * 64 + lane];
    float2 bb = ((const float2*)b)[lane];
    float2 a0, a1, a2, a3;
    a0.x = fmaf(self.x, s2, bb.x);
    a0.y = fmaf(self.y, s2, bb.y);
    a1.x = a1.y = a2.x = a2.y = a3.x = a3.y = 0.f;

    int beg = row_ptr[node];
    int end = row_ptr[node + 1];
    for (int i = beg; i < end; i += 8) {
        int s[8];
        float c[8];
#pragma unroll
        for (int u = 0; u < 8; ++u) {
            int idx = i + u;
            s[u] = csr_src[idx];                       // padded past NE with 0
            float cv = csr_coef[idx];
            c[u] = (idx < end) ? cv : 0.f;
        }
        float2 v0 = H2[(size_t)s[0] * 64 + lane];
        float2 v1 = H2[(size_t)s[1] * 64 + lane];
        float2 v2 = H2[(size_t)s[2] * 64 + lane];
        float2 v3 = H2[(size_t)s[3] * 64 + lane];
        float2 v4 = H2[(size_t)s[4] * 64 + lane];
        float2 v5 = H2[(size_t)s[5] * 64 + lane];
        float2 v6 = H2[(size_t)s[6] * 64 + lane];
        float2 v7 = H2[(size_t)s[7] * 64 + lane];
        a0.x = fmaf(v0.x, c[0], a0.x); a0.y = fmaf(v0.y, c[0], a0.y);
        a1.x = fmaf(v1.x, c[1], a1.x); a1.y = fmaf(v1.y, c[1], a1.y);
        a2.x = fmaf(v2.x, c[2], a2.x); a2.y = fmaf(v2.y, c[2], a2.y);
        a3.x = fmaf(v3.x, c[3], a3.x); a3.y = fmaf(v3.y, c[3], a3.y);
        a0.x = fmaf(v4.x, c[4], a0.x); a0.y = fmaf(v4.y, c[4], a0.y);
        a1.x = fmaf(v5.x, c[5], a1.x); a1.y = fmaf(v5.y, c[5], a1.y);
        a2.x = fmaf(v6.x, c[6], a2.x); a2.y = fmaf(v6.y, c[6], a2.y);
        a3.x = fmaf(v7.x, c[7], a3.x); a3.y = fmaf(v7.y, c[7], a3.y);
    }
    float2 r;
    r.x = (a0.x + a1.x) + (a2.x + a3.x);
    r.y = (a0.y + a1.y) + (a2.y + a3.y);
    ((float2*)out)[(size_t)node * 64 + lane] = r;
}

extern "C" void kernel_launch(void* const* d_in, const int* in_sizes, int n_in,
                              void* d_out, int out_size, void* d_ws, size_t ws_size,
                              hipStream_t stream) {
    const float* x  = (const float*)d_in[0];
    const int*   ei = (const int*)d_in[1];
    const float* W1 = (const float*)d_in[2];
    const float* b1 = (const float*)d_in[3];
    const float* W2 = (const float*)d_in[4];
    const float* b2 = (const float*)d_in[5];
    float* out = (float*)d_out;

    const int* src = ei;
    const int* dst = ei + NE;

    char* ws = (char*)d_ws;
    float* dinv      = (float*)(ws + 0);          // 200000 B
    int*   cnt       = (int*)  (ws + 204800);
    int*   row_ptr   = (int*)  (ws + 409600);     // NN+1 ints
    int*   cursor    = (int*)  (ws + 614400);
    int*   blockSums = (int*)  (ws + 819200);     // 784 B
    char*  wimg1     = (char*) (ws + 820224);     // 64 KB (bf16 hi+lo, swizzled)
    char*  wimg2     = (char*) (ws + 885760);     // 64 KB
    int*   csr_src   = (int*)  (ws + 951296);     // NE+8 ints
    float* csr_coef  = (float*)(ws + 4151328);    // NE+8 floats
    float* h         = (float*)(ws + 7351360);    // NN*D floats (25.6 MB)

    const int nBlkEdge = (NE + 255) / 256;   // 3125
    const int nBlkGemm = (NN + 63) / 64;     // 782
    const int nBlkPull = NN / 4;             // 12500

    // CSR build + norm + weight prep
    k_zero_cnt<<<NBLK, 256, 0, stream>>>(cnt);
    k_count<<<nBlkEdge, 256, 0, stream>>>(dst, cnt);
    k_dinv<<<NBLK, 256, 0, stream>>>(cnt, dinv);
    k_scan_partial<<<NBLK, 256, 0, stream>>>(cnt, blockSums);
    k_scan_blocks<<<1, 256, 0, stream>>>(blockSums, row_ptr, csr_src, csr_coef);
    k_scan_final<<<NBLK, 256, 0, stream>>>(cnt, blockSums, row_ptr, cursor);
    k_fill<<<nBlkEdge, 256, 0, stream>>>(src, dst, dinv, cursor, csr_src, csr_coef);
    k_prepw<<<128, 256, 0, stream>>>(W1, W2, wimg1, wimg2);

    // layer 1  (d_out doubles as the layer-1 aggregation buffer)
    k_mgemm<false><<<nBlkGemm, 256, 0, stream>>>(x, wimg1, h);
    k_pull<<<nBlkPull, 256, 0, stream>>>(h, dinv, b1, row_ptr, csr_src, csr_coef, out);

    // layer 2 (ReLU folded into GEMM A-fragment load)
    k_mgemm<true><<<nBlkGemm, 256, 0, stream>>>(out, wimg2, h);
    k_pull<<<nBlkPull, 256, 0, stream>>>(h, dinv, b2, row_ptr, csr_src, csr_coef, out);
}

// Round 4
// 255.353 us; speedup vs baseline: 11.2853x; 1.3976x over previous
//
#include <hip/hip_runtime.h>
#include <hip/hip_fp16.h>

#define NN 50000
#define NE 800000
#define D 128
#define NBLK ((NN + 255) / 256)   // 196 blocks over nodes

typedef __attribute__((ext_vector_type(8))) short bf16x8;
typedef __attribute__((ext_vector_type(4))) float f32x4;

static __device__ __forceinline__ unsigned short f2bf(float f) {
    unsigned u = __builtin_bit_cast(unsigned, f);
    unsigned r = (u + 0x7fffu + ((u >> 16) & 1u)) >> 16;   // RN-even
    return (unsigned short)r;
}
static __device__ __forceinline__ float bf2f(unsigned short h) {
    unsigned u = ((unsigned)h) << 16;
    return __builtin_bit_cast(float, u);
}

// ---------------- CSR build ----------------
__global__ __launch_bounds__(256) void k_zero_cnt(int* __restrict__ cnt) {
    int i = blockIdx.x * 256 + threadIdx.x;
    if (i < NN) cnt[i] = 0;
}

__global__ __launch_bounds__(256) void k_count(const int* __restrict__ dst, int* __restrict__ cnt) {
    int e = blockIdx.x * 256 + threadIdx.x;
    if (e < NE) atomicAdd(&cnt[dst[e]], 1);
}

__global__ __launch_bounds__(256) void k_scan_partial(const int* __restrict__ cnt, int* __restrict__ blockSums) {
    __shared__ int s[256];
    int t = threadIdx.x;
    int i = blockIdx.x * 256 + t;
    s[t] = (i < NN) ? cnt[i] : 0;
    __syncthreads();
    for (int off = 128; off > 0; off >>= 1) {
        if (t < off) s[t] += s[t + off];
        __syncthreads();
    }
    if (t == 0) blockSums[blockIdx.x] = s[0];
}

__global__ __launch_bounds__(256) void k_scan_blocks(int* __restrict__ blockSums, int* __restrict__ row_ptr,
                                                     int2* __restrict__ csr) {
    __shared__ int s[256];
    int t = threadIdx.x;
    int v = (t < NBLK) ? blockSums[t] : 0;
    s[t] = v;
    __syncthreads();
    for (int off = 1; off < 256; off <<= 1) {
        int y = (t >= off) ? s[t - off] : 0;
        __syncthreads();
        s[t] += y;
        __syncthreads();
    }
    if (t < NBLK) blockSums[t] = s[t] - v;  // exclusive block offsets
    if (t == 0) row_ptr[NN] = NE;
    if (t < 8) csr[NE + t] = make_int2(0, 0);  // zero unroll padding (coef bits = 0.0f)
}

// also computes dinv = rsqrt(deg+1)
__global__ __launch_bounds__(256) void k_scan_final(const int* __restrict__ cnt, const int* __restrict__ blockOffs,
                                                    int* __restrict__ row_ptr, int* __restrict__ cursor,
                                                    float* __restrict__ dinv) {
    __shared__ int s[256];
    int t = threadIdx.x;
    int i = blockIdx.x * 256 + t;
    int v = (i < NN) ? cnt[i] : 0;
    s[t] = v;
    __syncthreads();
    for (int off = 1; off < 256; off <<= 1) {
        int y = (t >= off) ? s[t - off] : 0;
        __syncthreads();
        s[t] += y;
        __syncthreads();
    }
    if (i < NN) {
        int excl = s[t] - v + blockOffs[blockIdx.x];
        row_ptr[i] = excl;
        cursor[i] = excl;
        dinv[i] = rsqrtf((float)v + 1.0f);
    }
}

__global__ __launch_bounds__(256) void k_fill(const int* __restrict__ src, const int* __restrict__ dst,
                                              const float* __restrict__ dinv, int* __restrict__ cursor,
                                              int2* __restrict__ csr) {
    int e = blockIdx.x * 256 + threadIdx.x;
    if (e < NE) {
        int sN = src[e], dN = dst[e];
        int pos = atomicAdd(&cursor[dN], 1);
        float c = dinv[sN] * dinv[dN];
        csr[pos] = make_int2(sN, __float_as_int(c));
    }
}

// ---------------- W prep: fp32 [k][n] -> swizzled bf16 hi/lo images of W^T [n][k] ----------------
__global__ __launch_bounds__(256) void k_prepw(const float* __restrict__ W1, const float* __restrict__ W2,
                                               char* __restrict__ img1, char* __restrict__ img2) {
    int b = blockIdx.x;
    const float* W = (b < 64) ? W1 : W2;
    char* img = (b < 64) ? img1 : img2;
    int e = (b & 63) * 256 + threadIdx.x;  // 0..16383
    int k = e >> 7, n = e & 127;
    float f = W[e];
    unsigned short hi = f2bf(f);
    float rem = f - bf2f(hi);
    unsigned short lo = f2bf(rem);
    unsigned off = (unsigned)((n << 8) + (k << 1)) ^ (unsigned)((n & 7) << 4);
    *(unsigned short*)(img + off) = hi;
    *(unsigned short*)(img + 32768 + off) = lo;
}

// ---------------- MFMA GEMM: H[M,128] = act(A[M,128]) @ W[128,128], bf16x3 split, fp16 out ----------------
template <bool RELU_IN>
__global__ __launch_bounds__(256) void k_mgemm(const float* __restrict__ A, const char* __restrict__ wimg,
                                               __half* __restrict__ H) {
    __shared__ char lds[65536];
    const int t = threadIdx.x;

    {   // stage both swizzled bf16 images (byte-identical copy)
        const float4* gv = (const float4*)wimg;
        float4* lv = (float4*)lds;
#pragma unroll
        for (int i = 0; i < 16; ++i) lv[i * 256 + t] = gv[i * 256 + t];
    }
    __syncthreads();

    const int lane = t & 63;
    const int wv = t >> 6;
    const int r0 = blockIdx.x * 64 + wv * 16;
    const int rl = lane & 15;              // A row in strip / C col
    const int g = lane >> 4;               // k-group 0..3
    int arow = r0 + rl;
    if (arow >= NN) arow = NN - 1;
    const float* ar = A + (size_t)arow * D + g * 8;

    f32x4 acc[8];
#pragma unroll
    for (int j = 0; j < 8; ++j) acc[j] = (f32x4){0.f, 0.f, 0.f, 0.f};

#pragma unroll
    for (int ks = 0; ks < 4; ++ks) {
        float av[8];
        float4 p0 = *(const float4*)(ar + ks * 32);
        float4 p1 = *(const float4*)(ar + ks * 32 + 4);
        av[0] = p0.x; av[1] = p0.y; av[2] = p0.z; av[3] = p0.w;
        av[4] = p1.x; av[5] = p1.y; av[6] = p1.z; av[7] = p1.w;
        bf16x8 ah, al;
#pragma unroll
        for (int i = 0; i < 8; ++i) {
            float a = RELU_IN ? fmaxf(av[i], 0.f) : av[i];
            unsigned short h = f2bf(a);
            ah[i] = (short)h;
            al[i] = (short)f2bf(a - bf2f(h));
        }
        const int kofs = (ks * 32 + g * 8) << 1;
#pragma unroll
        for (int j = 0; j < 8; ++j) {
            int n = j * 16 + rl;
            unsigned off = (unsigned)((n << 8) + kofs) ^ (unsigned)((n & 7) << 4);
            bf16x8 bh = *(const bf16x8*)(lds + off);
            bf16x8 bl = *(const bf16x8*)(lds + 32768 + off);
            acc[j] = __builtin_amdgcn_mfma_f32_16x16x32_bf16(ah, bh, acc[j], 0, 0, 0);
            acc[j] = __builtin_amdgcn_mfma_f32_16x16x32_bf16(ah, bl, acc[j], 0, 0, 0);
            acc[j] = __builtin_amdgcn_mfma_f32_16x16x32_bf16(al, bh, acc[j], 0, 0, 0);
        }
    }

    // C/D: col = lane&15, row = (lane>>4)*4 + reg
#pragma unroll
    for (int j = 0; j < 8; ++j) {
#pragma unroll
        for (int i = 0; i < 4; ++i) {
            int row = r0 + g * 4 + i;
            if (row < NN) H[(size_t)row * D + j * 16 + rl] = __float2half(acc[j][i]);
        }
    }
}

// ---------------- pull aggregation: one wave per node, fp16 table, 4-way unroll ----------------
__global__ __launch_bounds__(256) void k_pull(const __half2* __restrict__ H2, const float* __restrict__ dinv,
                                              const float* __restrict__ b, const int* __restrict__ row_ptr,
                                              const int2* __restrict__ csr, float* __restrict__ out) {
    int wid = (blockIdx.x * 256 + threadIdx.x) >> 6;
    int lane = threadIdx.x & 63;
    int node = __builtin_amdgcn_readfirstlane(wid);  // wave-uniform -> scalar loads

    float di = dinv[node];
    float s2 = di * di;
    float2 self = __half22float2(H2[(size_t)node * 64 + lane]);
    float2 bb = ((const float2*)b)[lane];
    float2 a0, a1;
    a0.x = fmaf(self.x, s2, bb.x);
    a0.y = fmaf(self.y, s2, bb.y);
    a1.x = a1.y = 0.f;

    int beg = row_ptr[node];
    int end = row_ptr[node + 1];
    for (int i = beg; i < end; i += 4) {
        int2 e0 = csr[i];
        int2 e1 = csr[i + 1];
        int2 e2 = csr[i + 2];
        int2 e3 = csr[i + 3];
        float c0 = __int_as_float(e0.y);
        float c1 = (i + 1 < end) ? __int_as_float(e1.y) : 0.f;
        float c2 = (i + 2 < end) ? __int_as_float(e2.y) : 0.f;
        float c3 = (i + 3 < end) ? __int_as_float(e3.y) : 0.f;
        float2 v0 = __half22float2(H2[(size_t)e0.x * 64 + lane]);
        float2 v1 = __half22float2(H2[(size_t)e1.x * 64 + lane]);
        float2 v2 = __half22float2(H2[(size_t)e2.x * 64 + lane]);
        float2 v3 = __half22float2(H2[(size_t)e3.x * 64 + lane]);
        a0.x = fmaf(v0.x, c0, a0.x); a0.y = fmaf(v0.y, c0, a0.y);
        a1.x = fmaf(v1.x, c1, a1.x); a1.y = fmaf(v1.y, c1, a1.y);
        a0.x = fmaf(v2.x, c2, a0.x); a0.y = fmaf(v2.y, c2, a0.y);
        a1.x = fmaf(v3.x, c3, a1.x); a1.y = fmaf(v3.y, c3, a1.y);
    }
    float2 r;
    r.x = a0.x + a1.x;
    r.y = a0.y + a1.y;
    ((float2*)out)[(size_t)node * 64 + lane] = r;
}

extern "C" void kernel_launch(void* const* d_in, const int* in_sizes, int n_in,
                              void* d_out, int out_size, void* d_ws, size_t ws_size,
                              hipStream_t stream) {
    const float* x  = (const float*)d_in[0];
    const int*   ei = (const int*)d_in[1];
    const float* W1 = (const float*)d_in[2];
    const float* b1 = (const float*)d_in[3];
    const float* W2 = (const float*)d_in[4];
    const float* b2 = (const float*)d_in[5];
    float* out = (float*)d_out;

    const int* src = ei;
    const int* dst = ei + NE;

    char* ws = (char*)d_ws;
    int*    cnt       = (int*)   (ws + 0);        // 200000 B
    int*    row_ptr   = (int*)   (ws + 204800);   // NN+1 ints
    int*    cursor    = (int*)   (ws + 409600);
    int*    blockSums = (int*)   (ws + 614400);   // 784 B
    float*  dinv      = (float*) (ws + 615424);   // 200000 B -> ends 815424
    char*   wimg1     = (char*)  (ws + 819200);   // 64 KB
    char*   wimg2     = (char*)  (ws + 884736);   // 64 KB
    int2*   csr       = (int2*)  (ws + 950272);   // (NE+8)*8 = 6400064 B -> ends 7350336
    __half* h         = (__half*)(ws + 7350400);  // NN*D fp16 = 12.8 MB
    __half2* h2       = (__half2*)h;

    const int nBlkEdge = (NE + 255) / 256;   // 3125
    const int nBlkGemm = (NN + 63) / 64;     // 782
    const int nBlkPull = NN / 4;             // 12500

    // CSR build + norm + weight prep
    k_zero_cnt<<<NBLK, 256, 0, stream>>>(cnt);
    k_count<<<nBlkEdge, 256, 0, stream>>>(dst, cnt);
    k_scan_partial<<<NBLK, 256, 0, stream>>>(cnt, blockSums);
    k_scan_blocks<<<1, 256, 0, stream>>>(blockSums, row_ptr, csr);
    k_scan_final<<<NBLK, 256, 0, stream>>>(cnt, blockSums, row_ptr, cursor, dinv);
    k_fill<<<nBlkEdge, 256, 0, stream>>>(src, dst, dinv, cursor, csr);
    k_prepw<<<128, 256, 0, stream>>>(W1, W2, wimg1, wimg2);

    // layer 1  (d_out doubles as the layer-1 aggregation buffer, fp32)
    k_mgemm<false><<<nBlkGemm, 256, 0, stream>>>(x, wimg1, h);
    k_pull<<<nBlkPull, 256, 0, stream>>>(h2, dinv, b1, row_ptr, csr, out);

    // layer 2 (ReLU folded into GEMM A-fragment load)
    k_mgemm<true><<<nBlkGemm, 256, 0, stream>>>(out, wimg2, h);
    k_pull<<<nBlkPull, 256, 0, stream>>>(h2, dinv, b2, row_ptr, csr, out);
}